// Round 5
// baseline (660.676 us; speedup 1.0000x reference)
//
#include <hip/hip_runtime.h>
#include <hip/hip_bf16.h>
#include <math.h>

// ---------------------------------------------------------------------------
// TransformerBlock fwd: ln1 -> qkv gemm -> causal flash attn -> proj+res
//   -> ln2 -> ffn1(buggy-gelu) -> ffn2+res.  bf16 MFMA, fp32 softmax/LN.
// R5: GEMM -> 8-phase interleaved schedule (T3+T4+T5+T2), dbuf=2:
//   per K-tile 4 quadrant-phases; stage units spread 1/phase; vmcnt(2) at
//   phases 4/8 only (before barrier -> globalizes). 256x256 (2Mx4N waves)
//   for qkv/ffn1; 128x256 for proj/ffn2 (tail-free 256-block grids).
// ---------------------------------------------------------------------------

typedef short bf16x8 __attribute__((ext_vector_type(8)));
typedef float f32x4 __attribute__((ext_vector_type(4)));
typedef short short4v __attribute__((ext_vector_type(4)));

#define MFMA16x32(a, b, c) __builtin_amdgcn_mfma_f32_16x16x32_bf16((a), (b), (c), 0, 0, 0)

__device__ __forceinline__ short f2bs(float f) {
    unsigned u = __builtin_bit_cast(unsigned, f);
    unsigned r = (u + 0x7FFFu + ((u >> 16) & 1u)) >> 16;
    return (short)(unsigned short)r;
}

__device__ __forceinline__ void gload_lds16(const void* g, void* l) {
    __builtin_amdgcn_global_load_lds(
        (const __attribute__((address_space(1))) unsigned int*)g,
        (__attribute__((address_space(3))) unsigned int*)l, 16, 0, 0);
}

// ---------- transpose fp32 (R x C) -> bf16 (C x R) ----------
__global__ __launch_bounds__(256) void transpose_kernel(const float* __restrict__ in,
                                                        short* __restrict__ out,
                                                        int R, int C) {
    __shared__ float tile[32][33];
    const int tx = threadIdx.x & 31;
    const int ty = threadIdx.x >> 5;
    const int c0 = blockIdx.x * 32;
    const int r0 = blockIdx.y * 32;
#pragma unroll
    for (int i = 0; i < 4; ++i) {
        int r = ty + i * 8;
        tile[r][tx] = in[(size_t)(r0 + r) * C + c0 + tx];
    }
    __syncthreads();
#pragma unroll
    for (int i = 0; i < 4; ++i) {
        int r = ty + i * 8;
        out[(size_t)(c0 + r) * R + r0 + tx] = f2bs(tile[tx][r]);
    }
}

// ---------- layernorm fp32 row (D=2048) -> bf16 row ----------
__global__ __launch_bounds__(256) void ln_kernel(const float* __restrict__ x,
                                                 const float* __restrict__ sc,
                                                 const float* __restrict__ sh,
                                                 short* __restrict__ out) {
    const int D = 2048;
    const int row = blockIdx.x;
    const int tid = threadIdx.x;
    __shared__ float red[4];
    const float4* xr = (const float4*)(x + (size_t)row * D);
    float4 v0 = xr[tid];
    float4 v1 = xr[tid + 256];
    float vals0[4] = {v0.x, v0.y, v0.z, v0.w};
    float vals1[4] = {v1.x, v1.y, v1.z, v1.w};

    float s = vals0[0] + vals0[1] + vals0[2] + vals0[3] + vals1[0] + vals1[1] + vals1[2] + vals1[3];
#pragma unroll
    for (int off = 32; off; off >>= 1) s += __shfl_xor(s, off);
    if ((tid & 63) == 0) red[tid >> 6] = s;
    __syncthreads();
    float mean = (red[0] + red[1] + red[2] + red[3]) * (1.0f / 2048.0f);
    __syncthreads();

    float q = 0.0f;
#pragma unroll
    for (int j = 0; j < 4; ++j) {
        float t0 = vals0[j] - mean;
        float t1 = vals1[j] - mean;
        q += t0 * t0 + t1 * t1;
    }
#pragma unroll
    for (int off = 32; off; off >>= 1) q += __shfl_xor(q, off);
    if ((tid & 63) == 0) red[tid >> 6] = q;
    __syncthreads();
    float var = (red[0] + red[1] + red[2] + red[3]) * (1.0f / 2048.0f);
    float inv = rsqrtf(var + 1e-5f);

    const int c0 = tid * 4;
    const int c1 = (tid + 256) * 4;
    short4v o0, o1;
#pragma unroll
    for (int j = 0; j < 4; ++j) {
        o0[j] = f2bs(sc[c0 + j] * ((vals0[j] - mean) * inv) + sh[c0 + j]);
        o1[j] = f2bs(sc[c1 + j] * ((vals1[j] - mean) * inv) + sh[c1 + j]);
    }
    *(short4v*)(out + (size_t)row * D + c0) = o0;
    *(short4v*)(out + (size_t)row * D + c1) = o1;
}

// ---------- bf16 GEMM, 8-phase schedule ----------
// C[M,N] = A[M,K] @ Bt[N,K]^T.  BK=64, 512 thr = 8 waves (2M x 4N).
// LDS dbuf=2: [A0 | A1(dbuf) | B0 | B1].  Even K-tiles -> buf0, odd -> buf1.
// Per K-tile 4 phases (quadrants qm,qn of the wave tile); ds_reads 12/8/4/0.
// Stage units (A-half0, A-half1, B-half0, B-half1) spread 1/phase:
//   ph1-3: tile t+1 u1..u3 -> dbuf1 (u0 staged at prev ph8)
//   ph4-7: tile t+2 u0..u3 -> dbuf0   (dbuf0 reads done by end-barrier ph3)
//   ph8:   tile t+3 u0     -> dbuf1   (dbuf1 reads done by end-barrier ph7)
// vmcnt(BM/128) before barrier at ph4 (t+1 landed) and ph8 (t+2 landed).
template <int BM, int BN, int EPI>
__global__ __launch_bounds__(512, 2) void gemm8p(const short* __restrict__ Aop,
                                                 const short* __restrict__ Bt,
                                                 int M, int N, int K,
                                                 void* __restrict__ Cout,
                                                 const float* __restrict__ bias,
                                                 const float* __restrict__ res,
                                                 float gconst) {
    constexpr int MF = BM / 32;   // m-frags per wave (2 waves in M)
    constexpr int NF = BN / 64;   // n-frags per wave (4 waves in N)
    constexpr int QM = MF / 2, QN = NF / 2;
    constexpr int ASZ = BM * 64;  // shorts per A buffer
    constexpr int BSZ = BN * 64;
    extern __shared__ __align__(16) short lds8[];
    short* const A0 = lds8;
    short* const A1 = lds8 + ASZ;
    short* const B0 = lds8 + 2 * ASZ;
    short* const B1 = lds8 + 2 * ASZ + BSZ;

    const int tid = threadIdx.x;
    const int lane = tid & 63;
    const int wid = tid >> 6;
    const int wm = wid >> 2, wn = wid & 3;
    const int l15 = lane & 15, grp = lane >> 4;

    // T1 XCD-bijective remap (grid %8 == 0 for all launches here)
    const int gx = gridDim.x;
    int flat = (int)blockIdx.y * gx + (int)blockIdx.x;
    const int cpx = (gx * (int)gridDim.y) >> 3;
    flat = (flat & 7) * cpx + (flat >> 3);
    const int bx = flat % gx, by = flat / gx;
    const long m0 = (long)by * BM, n0 = (long)bx * BN;

    f32x4 zero = {0.f, 0.f, 0.f, 0.f};
    f32x4 acc[MF][NF];
#pragma unroll
    for (int i = 0; i < MF; i++)
#pragma unroll
        for (int j = 0; j < NF; j++) acc[i][j] = zero;
    bf16x8 af[MF][2], bfr[NF][2];

    auto stA = [&](int t, int half, short* dst) {
        const long k0 = (long)t << 6;
#pragma unroll
        for (int j = 0; j < BM / 128; ++j) {
            int c = tid + j * 512;
            int row = c >> 3, sl = (c & 7) ^ (row & 7);
            gload_lds16(Aop + (size_t)(m0 + half * (BM / 2) + row) * K + k0 + sl * 8,
                        dst + (size_t)half * (BM / 2) * 64 + (size_t)c * 8);
        }
    };
    auto stB = [&](int t, int half, short* dst) {
        const long k0 = (long)t << 6;
#pragma unroll
        for (int j = 0; j < BN / 128; ++j) {
            int c = tid + j * 512;
            int row = c >> 3, sl = (c & 7) ^ (row & 7);
            gload_lds16(Bt + (size_t)(n0 + half * (BN / 2) + row) * K + k0 + sl * 8,
                        dst + (size_t)half * (BN / 2) * 64 + (size_t)c * 8);
        }
    };

#define LOADA(qm_, buf_)                                                      \
    _Pragma("unroll") for (int kk = 0; kk < 2; ++kk)                          \
    _Pragma("unroll") for (int mi = 0; mi < QM; ++mi) {                       \
        const int row = wm * (MF * 16) + ((qm_)*QM + mi) * 16 + l15;          \
        af[(qm_)*QM + mi][kk] = *(const bf16x8*)((buf_) + row * 64 +          \
            (((kk * 4 + grp) ^ (row & 7)) * 8));                              \
    }
#define LOADB(qn_, buf_)                                                      \
    _Pragma("unroll") for (int kk = 0; kk < 2; ++kk)                          \
    _Pragma("unroll") for (int ni = 0; ni < QN; ++ni) {                       \
        const int row = wn * (NF * 16) + ((qn_)*QN + ni) * 16 + l15;          \
        bfr[(qn_)*QN + ni][kk] = *(const bf16x8*)((buf_) + row * 64 +         \
            (((kk * 4 + grp) ^ (row & 7)) * 8));                              \
    }
#define QUADM(qm_, qn_)                                                       \
    _Pragma("unroll") for (int kk = 0; kk < 2; ++kk)                          \
    _Pragma("unroll") for (int mi = 0; mi < QM; ++mi)                         \
    _Pragma("unroll") for (int ni = 0; ni < QN; ++ni)                         \
        acc[(qm_)*QM + mi][(qn_)*QN + ni] =                                   \
            MFMA16x32(af[(qm_)*QM + mi][kk], bfr[(qn_)*QN + ni][kk],          \
                      acc[(qm_)*QM + mi][(qn_)*QN + ni]);
#define MIDTAIL(qm_, qn_)                                                     \
    __builtin_amdgcn_s_barrier();                                             \
    asm volatile("s_waitcnt lgkmcnt(0)" ::: "memory");                        \
    __builtin_amdgcn_sched_barrier(0);                                        \
    __builtin_amdgcn_s_setprio(1);                                            \
    QUADM(qm_, qn_);                                                          \
    __builtin_amdgcn_s_setprio(0);                                            \
    __builtin_amdgcn_s_barrier();
#define BARTAIL(qm_, qn_)                                                     \
    __builtin_amdgcn_s_barrier();                                             \
    __builtin_amdgcn_s_setprio(1);                                            \
    QUADM(qm_, qn_);                                                          \
    __builtin_amdgcn_s_setprio(0);                                            \
    __builtin_amdgcn_s_barrier();
#define VMW(lastf)                                                            \
    if (lastf) { asm volatile("s_waitcnt vmcnt(0)" ::: "memory"); }           \
    else if constexpr (BM == 256) { asm volatile("s_waitcnt vmcnt(2)" ::: "memory"); } \
    else { asm volatile("s_waitcnt vmcnt(1)" ::: "memory"); }

    const int nt2 = (K >> 6) >> 1;
    // prologue: tile0 fully, tile1 u0; then globalize tile0-landed.
    stA(0, 0, A0); stA(0, 1, A0); stB(0, 0, B0); stB(0, 1, B0);
    stA(1, 0, A1);
    VMW(false);
    __builtin_amdgcn_s_barrier();

    for (int i = 0; i < nt2; ++i) {
        const int t = 2 * i;
        const bool last = (i == nt2 - 1);
        // ph1
        stA(t + 1, 1, A1);
        LOADA(0, A0) LOADB(0, B0)
        MIDTAIL(0, 0)
        // ph2
        stB(t + 1, 0, B1);
        LOADA(1, A0)
        MIDTAIL(1, 0)
        // ph3
        stB(t + 1, 1, B1);
        LOADB(1, B0)
        MIDTAIL(0, 1)
        // ph4
        if (!last) stA(t + 2, 0, A0);
        VMW(last);
        BARTAIL(1, 1)
        // ph5
        if (!last) stA(t + 2, 1, A0);
        LOADA(0, A1) LOADB(0, B1)
        MIDTAIL(0, 0)
        // ph6
        if (!last) stB(t + 2, 0, B0);
        LOADA(1, A1)
        MIDTAIL(1, 0)
        // ph7
        if (!last) stB(t + 2, 1, B0);
        LOADB(1, B1)
        MIDTAIL(0, 1)
        // ph8
        if (!last) stA(t + 3, 0, A1);
        VMW(last);
        BARTAIL(1, 1)
    }

#pragma unroll
    for (int mi = 0; mi < MF; mi++) {
        long gr = m0 + wm * (MF * 16) + mi * 16 + grp * 4;
#pragma unroll
        for (int ni = 0; ni < NF; ni++) {
            long gcol = n0 + wn * (NF * 16) + ni * 16 + l15;
#pragma unroll
            for (int r = 0; r < 4; r++) {
                float vv = acc[mi][ni][r];
                long idx = (gr + r) * N + gcol;
                if (EPI == 0) {
                    ((short*)Cout)[idx] = f2bs(vv);
                } else if (EPI == 1) {
                    ((float*)Cout)[idx] = vv + bias[gcol] + res[idx];
                } else {
                    float tv = vv + bias[gcol];
                    float g = 0.5f * tv * (1.0f + gconst * (tv + 0.044715f * tv * tv * tv));
                    ((short*)Cout)[idx] = f2bs(g);
                }
            }
        }
    }
#undef LOADA
#undef LOADB
#undef QUADM
#undef MIDTAIL
#undef BARTAIL
#undef VMW
}

// ---------- reshape: qkv[4096,6144] K-cols -> Kh[32][2048][128] ----------
__global__ __launch_bounds__(256) void reshape_k_kernel(const short* __restrict__ qkv,
                                                        short* __restrict__ Kh) {
    size_t idx = ((size_t)blockIdx.x * 256 + threadIdx.x) * 8;
    int d = (int)(idx & 127);
    int s = (int)((idx >> 7) & 2047);
    int bh = (int)(idx >> 18);
    int b = bh >> 4, h = bh & 15;
    const short* src = qkv + (size_t)(b * 2048 + s) * 6144 + 2048 + h * 128 + d;
    *(bf16x8*)(Kh + idx) = *(const bf16x8*)src;
}

// ---------- reshape: qkv V-cols -> Vt[32][128][2048] (transposed) ----------
__global__ __launch_bounds__(256) void reshape_v_kernel(const short* __restrict__ qkv,
                                                        short* __restrict__ Vt) {
    __shared__ short tile[32][33];
    const int bid = blockIdx.x;
    const int dt = bid & 3, st = (bid >> 2) & 63, bh = bid >> 8;
    const int b = bh >> 4, h = bh & 15;
    const int s0 = st * 32, d0 = dt * 32;
    const int tx = threadIdx.x & 31, ty = threadIdx.x >> 5;
#pragma unroll
    for (int i = 0; i < 4; ++i) {
        int s = ty + i * 8;
        tile[s][tx] = qkv[(size_t)(b * 2048 + s0 + s) * 6144 + 4096 + h * 128 + d0 + tx];
    }
    __syncthreads();
#pragma unroll
    for (int i = 0; i < 4; ++i) {
        int d = ty + i * 8;
        Vt[((size_t)bh * 128 + d0 + d) * 2048 + s0 + tx] = tile[tx][d];
    }
}

// ---------- causal flash attention, paired q-tiles + double-buffered K/V ----
__global__ __launch_bounds__(256) void flash3_kernel(const short* __restrict__ qp,  // qkv, ld 6144
                                                     const short* __restrict__ Kh,  // [32][2048][128]
                                                     const short* __restrict__ Vt,  // [32][128][2048]
                                                     short* __restrict__ ctx) {
    const int S = 2048, D = 2048, HD = 128, LD = 6144;
    __shared__ __align__(16) short Ks[2][64 * 128];
    __shared__ __align__(16) short Vs[2][64 * 128];
    __shared__ __align__(16) short Ps[4][16 * 64];
    const int tid = threadIdx.x;
    const int lane = tid & 63, wid = tid >> 6;
    const int l15 = lane & 15, grp = lane >> 4;

    int bid = (int)blockIdx.x;
    bid = (bid & 7) * 64 + (bid >> 3);
    const int p = bid & 15, bh = bid >> 4;
    const int b = bh >> 4, h = bh & 15;
    const int qtH = 31 - p;
    const int nH = qtH + 1;
    const float scale = 0.08838834764831845f;
    const float NEGINF = -__builtin_inff();

    const short* Kbase = Kh + (size_t)bh * S * 128;
    const short* Vbase = Vt + (size_t)bh * 128 * S;
    short* Psw = &Ps[wid][0];

    f32x4 zero = {0.f, 0.f, 0.f, 0.f};
    bf16x8 aq[4];
    float m_[4], l_[4];
    f32x4 o[8];

    int qt = qtH;
    int qw = qt * 64 + wid * 16;
    {
        const short* qrow = qp + (size_t)(b * S + qw + l15) * LD + h * HD;
#pragma unroll
        for (int kc = 0; kc < 4; kc++) aq[kc] = *(const bf16x8*)(qrow + kc * 32 + grp * 8);
    }
#pragma unroll
    for (int r = 0; r < 4; r++) { m_[r] = NEGINF; l_[r] = 0.f; }
#pragma unroll
    for (int n = 0; n < 8; n++) o[n] = zero;

#pragma unroll
    for (int j = 0; j < 4; ++j) {
        int c = tid + j * 256;
        int r = c >> 4, sl = c & 15;
        gload_lds16(Kbase + (size_t)r * 128 + ((sl ^ (r & 7)) * 8),
                    Ks[0] + (size_t)(wid * 64 + j * 256) * 8);
    }
#pragma unroll
    for (int j = 0; j < 4; ++j) {
        int c = tid + j * 256;
        int d = c >> 3, sl = c & 7;
        gload_lds16(Vbase + (size_t)d * S + ((sl ^ (d & 7)) * 8),
                    Vs[0] + (size_t)(wid * 64 + j * 256) * 8);
    }
    __syncthreads();

    int cur = 0;
    for (int i = 0; i < 33; ++i) {
        const int kt = (i < nH) ? i : (i - nH);
        const bool lastT = (kt == qt);

        if (i + 1 < 33) {
            const int ktn = (i + 1 < nH) ? (i + 1) : (i + 1 - nH);
            const long kn0 = (long)ktn * 64;
            const short* Kg = Kbase + kn0 * 128;
            const short* Vg = Vbase + kn0;
            short* kd = Ks[cur ^ 1];
            short* vd = Vs[cur ^ 1];
#pragma unroll
            for (int j = 0; j < 4; ++j) {
                int c = tid + j * 256;
                int r = c >> 4, sl = c & 15;
                gload_lds16(Kg + (size_t)r * 128 + ((sl ^ (r & 7)) * 8),
                            kd + (size_t)(wid * 64 + j * 256) * 8);
            }
#pragma unroll
            for (int j = 0; j < 4; ++j) {
                int c = tid + j * 256;
                int d = c >> 3, sl = c & 7;
                gload_lds16(Vg + (size_t)d * S + ((sl ^ (d & 7)) * 8),
                            vd + (size_t)(wid * 64 + j * 256) * 8);
            }
        }

        const short* Kc = Ks[cur];
        const short* Vc = Vs[cur];

        f32x4 s[4] = {zero, zero, zero, zero};
#pragma unroll
        for (int n = 0; n < 4; ++n) {
            int r = n * 16 + l15;
#pragma unroll
            for (int kc = 0; kc < 4; ++kc) {
                bf16x8 kb = *(const bf16x8*)(Kc + r * 128 + (((kc * 4 + grp) ^ (r & 7)) * 8));
                s[n] = MFMA16x32(aq[kc], kb, s[n]);
            }
        }

        float al[4];
#pragma unroll
        for (int r = 0; r < 4; ++r) {
            float v[4];
#pragma unroll
            for (int n = 0; n < 4; ++n) v[n] = s[n][r] * scale;
            if (lastT) {
                int qrel = wid * 16 + grp * 4 + r;
#pragma unroll
                for (int n = 0; n < 4; ++n)
                    if (n * 16 + l15 > qrel) v[n] = NEGINF;
            }
            float mx = fmaxf(fmaxf(v[0], v[1]), fmaxf(v[2], v[3]));
            mx = fmaxf(mx, __shfl_xor(mx, 1));
            mx = fmaxf(mx, __shfl_xor(mx, 2));
            mx = fmaxf(mx, __shfl_xor(mx, 4));
            mx = fmaxf(mx, __shfl_xor(mx, 8));
            float mn = fmaxf(m_[r], mx);
            float sc_ = __expf(m_[r] - mn);
            float rs = 0.f;
            int q = grp * 4 + r;
#pragma unroll
            for (int n = 0; n < 4; ++n) {
                v[n] = __expf(v[n] - mn);
                rs += v[n];
                Psw[q * 64 + (((n * 2 + (l15 >> 3)) ^ (q & 7)) * 8) + (l15 & 7)] = f2bs(v[n]);
            }
            rs += __shfl_xor(rs, 1);
            rs += __shfl_xor(rs, 2);
            rs += __shfl_xor(rs, 4);
            rs += __shfl_xor(rs, 8);
            l_[r] = l_[r] * sc_ + rs;
            m_[r] = mn;
            al[r] = sc_;
        }
#pragma unroll
        for (int n = 0; n < 8; n++) {
            f32x4 t = o[n];
            t[0] *= al[0]; t[1] *= al[1]; t[2] *= al[2]; t[3] *= al[3];
            o[n] = t;
        }

        bf16x8 pa[2];
#pragma unroll
        for (int kc = 0; kc < 2; ++kc)
            pa[kc] = *(const bf16x8*)(Psw + l15 * 64 + (((kc * 4 + grp) ^ (l15 & 7)) * 8));
#pragma unroll
        for (int n = 0; n < 8; ++n) {
            int d = n * 16 + l15;
#pragma unroll
            for (int kc = 0; kc < 2; ++kc) {
                bf16x8 vb = *(const bf16x8*)(Vc + d * 64 + (((kc * 4 + grp) ^ (d & 7)) * 8));
                o[n] = MFMA16x32(pa[kc], vb, o[n]);
            }
        }

        if (lastT) {
            float inv[4];
#pragma unroll
            for (int r = 0; r < 4; ++r) inv[r] = 1.0f / l_[r];
            short* cb_ = ctx + (size_t)(b * S + qw + grp * 4) * D + h * HD + l15;
#pragma unroll
            for (int n = 0; n < 8; ++n)
#pragma unroll
                for (int r = 0; r < 4; ++r)
                    cb_[(size_t)r * D + n * 16] = f2bs(o[n][r] * inv[r]);
            if (i < 32) {
                qt = 31 - qtH;
                qw = qt * 64 + wid * 16;
                const short* qrow = qp + (size_t)(b * S + qw + l15) * LD + h * HD;
#pragma unroll
                for (int kc = 0; kc < 4; kc++) aq[kc] = *(const bf16x8*)(qrow + kc * 32 + grp * 8);
#pragma unroll
                for (int r = 0; r < 4; r++) { m_[r] = NEGINF; l_[r] = 0.f; }
#pragma unroll
                for (int n = 0; n < 8; n++) o[n] = zero;
            }
        }
        __syncthreads();
        cur ^= 1;
    }
}

// ---------------------------------------------------------------------------
extern "C" void kernel_launch(void* const* d_in, const int* in_sizes, int n_in,
                              void* d_out, int out_size, void* d_ws, size_t ws_size,
                              hipStream_t stream) {
    const float* x    = (const float*)d_in[0];
    const float* wq   = (const float*)d_in[1];
    const float* wk   = (const float*)d_in[2];
    const float* wv   = (const float*)d_in[3];
    const float* wo   = (const float*)d_in[4];
    const float* bo   = (const float*)d_in[5];
    const float* w1   = (const float*)d_in[6];
    const float* b1   = (const float*)d_in[7];
    const float* w2   = (const float*)d_in[8];
    const float* b2   = (const float*)d_in[9];
    const float* lnsc = (const float*)d_in[10];
    const float* lnsh = (const float*)d_in[11];

    const int B = 2, S = 2048, D = 2048;
    const int M = B * S;  // 4096
    const int LDS_BIG = 2 * (256 * 64 + 256 * 64) * 2;  // 131072
    const int LDS_SML = 2 * (128 * 64 + 256 * 64) * 2;  // 98304

    char* p = (char*)d_ws;
    short* wqkvT = (short*)p; p += (size_t)3 * D * D * 2;   // dead after qkv gemm
    short* woT   = (short*)p; p += (size_t)D * D * 2;
    short* w1T   = (short*)p; p += (size_t)4 * D * D * 2;
    short* w2T   = (short*)p; p += (size_t)4 * D * D * 2;
    short* lnb   = (short*)p; p += (size_t)M * D * 2;
    short* qkvb  = (short*)p;
    short* h1    = qkvb;                                    // reuse qkv+ctx span
    p += (size_t)M * 3 * D * 2;
    short* ctxb  = (short*)p; p += (size_t)M * D * 2;
    float* x2    = (float*)p; p += (size_t)M * D * 4;

    short* Kh = wqkvT;          // overlays wqkvT (dead after qkv gemm)
    short* Vt = (short*)x2;     // overlays x2 (written only by proj, after flash)

    const float gconst = tanhf(sqrtf(2.0f / 3.14159265358979323846f));

    hipFuncSetAttribute((const void*)&gemm8p<256, 256, 0>, hipFuncAttributeMaxDynamicSharedMemorySize, LDS_BIG);
    hipFuncSetAttribute((const void*)&gemm8p<256, 256, 2>, hipFuncAttributeMaxDynamicSharedMemorySize, LDS_BIG);
    hipFuncSetAttribute((const void*)&gemm8p<128, 256, 1>, hipFuncAttributeMaxDynamicSharedMemorySize, LDS_SML);

    dim3 blk(256);
    transpose_kernel<<<dim3(64, 64), blk, 0, stream>>>(wq, wqkvT, D, D);
    transpose_kernel<<<dim3(64, 64), blk, 0, stream>>>(wk, wqkvT + (size_t)D * D, D, D);
    transpose_kernel<<<dim3(64, 64), blk, 0, stream>>>(wv, wqkvT + (size_t)2 * D * D, D, D);
    transpose_kernel<<<dim3(64, 64), blk, 0, stream>>>(wo, woT, D, D);
    transpose_kernel<<<dim3(256, 64), blk, 0, stream>>>(w1, w1T, D, 4 * D);
    transpose_kernel<<<dim3(64, 256), blk, 0, stream>>>(w2, w2T, 4 * D, D);

    ln_kernel<<<dim3(M), blk, 0, stream>>>(x, lnsc, lnsh, lnb);
    // qkv: [4096,2048]@[2048,6144] -> grid 24x16 (384)
    gemm8p<256, 256, 0><<<dim3(3 * D / 256, M / 256), dim3(512), LDS_BIG, stream>>>(
        lnb, wqkvT, M, 3 * D, D, qkvb, nullptr, nullptr, 0.f);

    reshape_k_kernel<<<dim3(4096), blk, 0, stream>>>(qkvb, Kh);
    reshape_v_kernel<<<dim3(8192), blk, 0, stream>>>(qkvb, Vt);

    flash3_kernel<<<dim3(512), blk, 0, stream>>>(qkvb, Kh, Vt, ctxb);

    // proj: grid 8x32 (256)
    gemm8p<128, 256, 1><<<dim3(D / 256, M / 128), dim3(512), LDS_SML, stream>>>(
        ctxb, woT, M, D, D, x2, bo, x, 0.f);
    ln_kernel<<<dim3(M), blk, 0, stream>>>(x2, lnsc, lnsh, lnb);
    // ffn1: grid 32x16 (512)
    gemm8p<256, 256, 2><<<dim3(4 * D / 256, M / 256), dim3(512), LDS_BIG, stream>>>(
        lnb, w1T, M, 4 * D, D, h1, b1, nullptr, gconst);
    // ffn2: grid 8x32 (256)
    gemm8p<128, 256, 1><<<dim3(D / 256, M / 128), dim3(512), LDS_SML, stream>>>(
        h1, w2T, M, D, 4 * D, (float*)d_out, b2, x2, 0.f);
}